// Round 5
// baseline (1269.742 us; speedup 1.0000x reference)
//
#include <hip/hip_runtime.h>

#define B_ 128
#define S_ 500
#define D_ 32
#define H_ 8
#define FCIN (S_ * D_)          // 16000
#define HID 1024

// ---------------------------------------------------------------------------
// K1: fused QKV + attention, all fp32 VALU. Block per (b,h), 128 threads,
// 4 sequence positions per thread. K/V staged in LDS; q pre-scaled by
// 0.5*log2(e) so exp(score*0.5) == exp2(q.k). Single-pass softmax
// (|score/2| < ~3, no overflow; no max subtraction needed).
// ---------------------------------------------------------------------------
__global__ __launch_bounds__(128) void attn_fused(
    const float* __restrict__ x,
    const float* __restrict__ Wq, const float* __restrict__ bq,
    const float* __restrict__ Wk, const float* __restrict__ bk,
    const float* __restrict__ Wv, const float* __restrict__ bv,
    float* __restrict__ av)
{
    __shared__ float  sW[12 * 32];      // rows 0-3 Wq[h*4+j], 4-7 Wk, 8-11 Wv
    __shared__ float  sB[12];
    __shared__ float4 skv4[S_ * 2];     // [key][0]=k4, [key][1]=v4 : 16 KB
    float* skv = (float*)skv4;

    int tid = threadIdx.x;
    int bh = blockIdx.x;
    int b = bh >> 3, h = bh & 7;

    for (int i = tid; i < 384; i += 128) {
        int r = i >> 5, d = i & 31;
        const float* src = (r < 4) ? (Wq + (h * 4 + r) * 32)
                         : (r < 8) ? (Wk + (h * 4 + r - 4) * 32)
                                   : (Wv + (h * 4 + r - 8) * 32);
        sW[r * 32 + d] = src[d];
    }
    if (tid < 12) {
        int r = tid;
        sB[r] = (r < 4) ? bq[h * 4 + r] : (r < 8) ? bk[h * 4 + r - 4]
                                                  : bv[h * 4 + r - 8];
    }
    __syncthreads();

    float qreg[4][4];
    int   sidx[4];
    bool  sval[4];
#pragma unroll
    for (int c = 0; c < 4; ++c) {
        int s = tid + c * 128;
        sval[c] = (s < S_);
        int sc = sval[c] ? s : 0;
        sidx[c] = sc;
        const float* xr = x + (b * S_ + sc) * 32;
        float xv[32];
#pragma unroll
        for (int d = 0; d < 32; ++d) xv[d] = xr[d];
#pragma unroll
        for (int j = 0; j < 4; ++j) {
            float aq = sB[j], ak = sB[4 + j], avv = sB[8 + j];
#pragma unroll
            for (int d = 0; d < 32; ++d) {
                aq  += xv[d] * sW[j * 32 + d];
                ak  += xv[d] * sW[(4 + j) * 32 + d];
                avv += xv[d] * sW[(8 + j) * 32 + d];
            }
            qreg[c][j] = aq * 0.72134752044448169f;   // 0.5 * log2(e)
            if (sval[c]) {
                skv[sc * 8 + j]     = ak;
                skv[sc * 8 + 4 + j] = avv;
            }
        }
    }
    __syncthreads();

    float sum[4]  = {0.f, 0.f, 0.f, 0.f};
    float acc0[4] = {0.f, 0.f, 0.f, 0.f};
    float acc1[4] = {0.f, 0.f, 0.f, 0.f};
    float acc2[4] = {0.f, 0.f, 0.f, 0.f};
    float acc3[4] = {0.f, 0.f, 0.f, 0.f};

    for (int key = 0; key < S_; ++key) {
        float4 kk = skv4[key * 2];
        float4 vv = skv4[key * 2 + 1];
#pragma unroll
        for (int c = 0; c < 4; ++c) {
            float sc = qreg[c][0] * kk.x + qreg[c][1] * kk.y
                     + qreg[c][2] * kk.z + qreg[c][3] * kk.w;
            float e = exp2f(sc);
            sum[c]  += e;
            acc0[c] += e * vv.x; acc1[c] += e * vv.y;
            acc2[c] += e * vv.z; acc3[c] += e * vv.w;
        }
    }

#pragma unroll
    for (int c = 0; c < 4; ++c) {
        if (!sval[c]) continue;
        float r = 1.0f / sum[c];
        float* o = av + (b * S_ + sidx[c]) * 32 + h * 4;
        o[0] = acc0[c] * r; o[1] = acc1[c] * r;
        o[2] = acc2[c] * r; o[3] = acc3[c] * r;
    }
}

// ---------------------------------------------------------------------------
// K2: output projection, fp32 VALU. One thread per element of flat
// ([64000 rows][32 cols]): flat[row][d] = av[row][:] . Wo[d][:] + bo[d].
// ---------------------------------------------------------------------------
__global__ __launch_bounds__(256) void proj_kernel(
    const float* __restrict__ av, const float* __restrict__ Wo,
    const float* __restrict__ bo, float* __restrict__ flat)
{
    int id = blockIdx.x * 256 + threadIdx.x;   // < 2,048,000
    int row = id >> 5, d = id & 31;
    const float* ar = av + row * 32;
    const float* wr = Wo + d * 32;
    float acc = bo[d];
#pragma unroll
    for (int k = 0; k < 32; ++k) acc += ar[k] * wr[k];
    flat[id] = acc;                            // id == row*32 + d
}

// ---------------------------------------------------------------------------
// K3: FC1, fp32 VALU. Block = (m, j-quad): stages flat[m] (62.5 KB) in LDS,
// each thread computes one hidden[m][j] with a 16000-term dot against W1[j].
// ---------------------------------------------------------------------------
__global__ __launch_bounds__(256) void fc1_kernel(
    const float* __restrict__ flat, const float* __restrict__ W1,
    const float* __restrict__ b1, float* __restrict__ hidden)
{
    __shared__ float4 sflat4[FCIN / 4];        // 62.5 KB
    float* sflat = (float*)sflat4;

    int m  = blockIdx.x >> 2;
    int jq = blockIdx.x & 3;
    for (int i = threadIdx.x; i < FCIN; i += 256) sflat[i] = flat[m * FCIN + i];
    __syncthreads();

    int j = jq * 256 + threadIdx.x;
    const float* w = W1 + (size_t)j * FCIN;
    float acc = b1[j];
    for (int p = 0; p < FCIN; p += 4) {
        float4 wv = *(const float4*)(w + p);
        float4 fv = sflat4[p >> 2];
        acc += fv.x * wv.x + fv.y * wv.y + fv.z * wv.z + fv.w * wv.w;
    }
    hidden[m * HID + j] = acc;
}

// ---------------------------------------------------------------------------
// K4: FC2 + FC3, fp32 VALU. Block = 4 m-rows x 64 c-lanes; wave
// shuffle-reduce for the 2-wide final output.
// d_out (fp32): [0,8192) = out1, [8192,8448) = out.
// ---------------------------------------------------------------------------
__global__ __launch_bounds__(256) void fc2_kernel(
    const float* __restrict__ hidden,
    const float* __restrict__ W2, const float* __restrict__ b2,
    const float* __restrict__ W3, const float* __restrict__ b3,
    float* __restrict__ out)
{
    int tid = threadIdx.x;
    int c = tid & 63;
    int m = blockIdx.x * 4 + (tid >> 6);
    const float* hrow = hidden + m * HID;
    const float* wrow = W2 + c * HID;

    float acc = b2[c];
    for (int p = 0; p < HID; p += 4) {
        float4 wv = *(const float4*)(wrow + p);
        float4 hv = *(const float4*)(hrow + p);
        acc += hv.x * wv.x + hv.y * wv.y + hv.z * wv.z + hv.w * wv.w;
    }
    out[m * 64 + c] = acc;

    float t0 = acc * W3[c];
    float t1 = acc * W3[64 + c];
#pragma unroll
    for (int off = 32; off > 0; off >>= 1) {
        t0 += __shfl_down(t0, off, 64);
        t1 += __shfl_down(t1, off, 64);
    }
    if (c == 0) {
        float2 pk;
        pk.x = t0 + b3[0];
        pk.y = t1 + b3[1];
        *(float2*)(out + 8192 + m * 2) = pk;
    }
}

// ---------------------------------------------------------------------------
extern "C" void kernel_launch(void* const* d_in, const int* in_sizes, int n_in,
                              void* d_out, int out_size, void* d_ws, size_t ws_size,
                              hipStream_t stream) {
    const float* x  = (const float*)d_in[0];
    const float* Wq = (const float*)d_in[1];
    const float* bq = (const float*)d_in[2];
    const float* Wk = (const float*)d_in[3];
    const float* bk = (const float*)d_in[4];
    const float* Wv = (const float*)d_in[5];
    const float* bv = (const float*)d_in[6];
    const float* Wo = (const float*)d_in[7];
    const float* bo = (const float*)d_in[8];
    const float* W1 = (const float*)d_in[9];
    const float* b1 = (const float*)d_in[10];
    const float* W2 = (const float*)d_in[11];
    const float* b2 = (const float*)d_in[12];
    const float* W3 = (const float*)d_in[13];
    const float* b3 = (const float*)d_in[14];
    float* out = (float*)d_out;

    // ws layout (bytes), total 16,384,000:
    //   [0,          8,192,000)  av fp32 [64000][32]  -> overlaid by hidden
    //   [8,192,000, 16,384,000)  flat fp32 [128][16000]
    float* av     = (float*)d_ws;
    float* flat   = (float*)((char*)d_ws + 8192000);
    float* hidden = (float*)d_ws;   // overlays av; written by fc1 (reads only
                                    // flat), read by fc2 — stream-ordered safe

    attn_fused <<<dim3(1024), dim3(128), 0, stream>>>(x, Wq, bq, Wk, bk, Wv, bv, av);
    proj_kernel<<<dim3(8000), dim3(256), 0, stream>>>(av, Wo, bo, flat);
    fc1_kernel <<<dim3(512),  dim3(256), 0, stream>>>(flat, W1, b1, hidden);
    fc2_kernel <<<dim3(32),   dim3(256), 0, stream>>>(hidden, W2, b2, W3, b3, out);
}

// Round 6
// 460.646 us; speedup vs baseline: 2.7564x; 2.7564x over previous
//
#include <hip/hip_runtime.h>

typedef unsigned short u16;
typedef __attribute__((ext_vector_type(8))) short short8;
typedef __attribute__((ext_vector_type(4))) float floatx4;

#define B_ 128
#define S_ 500
#define D_ 32
#define H_ 8
#define FCIN (S_ * D_)          // 16000
#define HID 1024

__device__ __forceinline__ u16 f2bf(float f) {
    union { float f; unsigned u; } x;
    x.f = f;
    unsigned u = x.u;
    return (u16)((u + 0x7fff + ((u >> 16) & 1)) >> 16);
}

// ---------------------------------------------------------------------------
// K1: fused QKV + attention, all fp32 VALU (unchanged from passing R5).
// ---------------------------------------------------------------------------
__global__ __launch_bounds__(128) void attn_fused(
    const float* __restrict__ x,
    const float* __restrict__ Wq, const float* __restrict__ bq,
    const float* __restrict__ Wk, const float* __restrict__ bk,
    const float* __restrict__ Wv, const float* __restrict__ bv,
    float* __restrict__ av)
{
    __shared__ float  sW[12 * 32];      // rows 0-3 Wq[h*4+j], 4-7 Wk, 8-11 Wv
    __shared__ float  sB[12];
    __shared__ float4 skv4[S_ * 2];     // [key][0]=k4, [key][1]=v4 : 16 KB
    float* skv = (float*)skv4;

    int tid = threadIdx.x;
    int bh = blockIdx.x;
    int b = bh >> 3, h = bh & 7;

    for (int i = tid; i < 384; i += 128) {
        int r = i >> 5, d = i & 31;
        const float* src = (r < 4) ? (Wq + (h * 4 + r) * 32)
                         : (r < 8) ? (Wk + (h * 4 + r - 4) * 32)
                                   : (Wv + (h * 4 + r - 8) * 32);
        sW[r * 32 + d] = src[d];
    }
    if (tid < 12) {
        int r = tid;
        sB[r] = (r < 4) ? bq[h * 4 + r] : (r < 8) ? bk[h * 4 + r - 4]
                                                  : bv[h * 4 + r - 8];
    }
    __syncthreads();

    float qreg[4][4];
    int   sidx[4];
    bool  sval[4];
#pragma unroll
    for (int c = 0; c < 4; ++c) {
        int s = tid + c * 128;
        sval[c] = (s < S_);
        int sc = sval[c] ? s : 0;
        sidx[c] = sc;
        const float* xr = x + (b * S_ + sc) * 32;
        float xv[32];
#pragma unroll
        for (int d = 0; d < 32; ++d) xv[d] = xr[d];
#pragma unroll
        for (int j = 0; j < 4; ++j) {
            float aq = sB[j], ak = sB[4 + j], avv = sB[8 + j];
#pragma unroll
            for (int d = 0; d < 32; ++d) {
                aq  += xv[d] * sW[j * 32 + d];
                ak  += xv[d] * sW[(4 + j) * 32 + d];
                avv += xv[d] * sW[(8 + j) * 32 + d];
            }
            qreg[c][j] = aq * 0.72134752044448169f;   // 0.5 * log2(e)
            if (sval[c]) {
                skv[sc * 8 + j]     = ak;
                skv[sc * 8 + 4 + j] = avv;
            }
        }
    }
    __syncthreads();

    float sum[4]  = {0.f, 0.f, 0.f, 0.f};
    float acc0[4] = {0.f, 0.f, 0.f, 0.f};
    float acc1[4] = {0.f, 0.f, 0.f, 0.f};
    float acc2[4] = {0.f, 0.f, 0.f, 0.f};
    float acc3[4] = {0.f, 0.f, 0.f, 0.f};

    for (int key = 0; key < S_; ++key) {
        float4 kk = skv4[key * 2];
        float4 vv = skv4[key * 2 + 1];
#pragma unroll
        for (int c = 0; c < 4; ++c) {
            float sc = qreg[c][0] * kk.x + qreg[c][1] * kk.y
                     + qreg[c][2] * kk.z + qreg[c][3] * kk.w;
            float e = exp2f(sc);
            sum[c]  += e;
            acc0[c] += e * vv.x; acc1[c] += e * vv.y;
            acc2[c] += e * vv.z; acc3[c] += e * vv.w;
        }
    }

#pragma unroll
    for (int c = 0; c < 4; ++c) {
        if (!sval[c]) continue;
        float r = 1.0f / sum[c];
        float* o = av + (b * S_ + sidx[c]) * 32 + h * 4;
        o[0] = acc0[c] * r; o[1] = acc1[c] * r;
        o[2] = acc2[c] * r; o[3] = acc3[c] * r;
    }
}

// ---------------------------------------------------------------------------
// K2: output projection, fp32 VALU -> flat stored as bf16 (feeds MFMA fc1).
// Also inits hidden[m][j] = b1[j] for fc1's atomic accumulation.
// ---------------------------------------------------------------------------
__global__ __launch_bounds__(256) void proj_kernel(
    const float* __restrict__ av, const float* __restrict__ Wo,
    const float* __restrict__ bo, const float* __restrict__ b1,
    u16* __restrict__ flatbf, float* __restrict__ hidden)
{
    int id = blockIdx.x * 256 + threadIdx.x;   // < 2,048,000
    if (id < B_ * HID) hidden[id] = b1[id & (HID - 1)];

    int row = id >> 5, d = id & 31;
    const float* ar = av + row * 32;
    const float* wr = Wo + d * 32;
    float acc = bo[d];
#pragma unroll
    for (int k = 0; k < 32; ++k) acc += ar[k] * wr[k];
    flatbf[id] = f2bf(acc);                    // id == row*32 + d == m*FCIN + p
}

// ---------------------------------------------------------------------------
// K3: FC1 via MFMA 16x16x32 bf16, split-K.
// C[128x1024] += flat[128x16000] @ W1^T.  Grid 320 = 16 n-groups x 20
// k-chunks; 4 waves/block, each wave: one 16-wide n-tile x all 128 m rows
// (8 MFMA/step x 25 steps of K=32). W1 read EXACTLY once from HBM (65.5 MB).
// A = flat bf16 (direct short8 loads); B = W1 fp32 -> bf16 in-register.
// Epilogue: fp32 atomicAdd into b1-initialized hidden.
// ---------------------------------------------------------------------------
__global__ __launch_bounds__(256) void fc1_mfma(
    const u16* __restrict__ flatbf, const float* __restrict__ W1,
    float* __restrict__ hidden)
{
    int tid = threadIdx.x;
    int wid = tid >> 6, lane = tid & 63;
    int lm = lane & 15, kq = lane >> 4;
    int ng = blockIdx.x & 15, kc = blockIdx.x >> 4;   // kc in [0,20)
    int n0 = ng * 64 + wid * 16;

    floatx4 acc[8];
#pragma unroll
    for (int mt = 0; mt < 8; ++mt) acc[mt] = (floatx4){0.f, 0.f, 0.f, 0.f};

    const float* wrow = W1 + (size_t)(n0 + lm) * FCIN;
    const u16*  abase = flatbf + lm * FCIN;

    for (int step = 0; step < 25; ++step) {
        int kk = kc * 800 + step * 32 + kq * 8;
        // B-frag: W1[n0+lm][kk..kk+8) fp32 -> bf16
        float4 w0 = *(const float4*)(wrow + kk);
        float4 w1 = *(const float4*)(wrow + kk + 4);
        short8 bfr;
        bfr[0] = (short)f2bf(w0.x); bfr[1] = (short)f2bf(w0.y);
        bfr[2] = (short)f2bf(w0.z); bfr[3] = (short)f2bf(w0.w);
        bfr[4] = (short)f2bf(w1.x); bfr[5] = (short)f2bf(w1.y);
        bfr[6] = (short)f2bf(w1.z); bfr[7] = (short)f2bf(w1.w);
#pragma unroll
        for (int mt = 0; mt < 8; ++mt) {
            short8 afr = *(const short8*)(abase + mt * 16 * FCIN + kk);
            acc[mt] = __builtin_amdgcn_mfma_f32_16x16x32_bf16(afr, bfr, acc[mt], 0, 0, 0);
        }
    }

    int j = n0 + lm;                       // C col = lane&15
#pragma unroll
    for (int mt = 0; mt < 8; ++mt) {
#pragma unroll
        for (int r = 0; r < 4; ++r) {
            int m = mt * 16 + kq * 4 + r;  // C row = (lane>>4)*4 + r
            atomicAdd(&hidden[m * HID + j], acc[mt][r]);
        }
    }
}

// ---------------------------------------------------------------------------
// K4: FC2 + FC3, fp32 VALU (unchanged). d_out fp32: [0,8192)=out1,
// [8192,8448)=out.
// ---------------------------------------------------------------------------
__global__ __launch_bounds__(256) void fc2_kernel(
    const float* __restrict__ hidden,
    const float* __restrict__ W2, const float* __restrict__ b2,
    const float* __restrict__ W3, const float* __restrict__ b3,
    float* __restrict__ out)
{
    int tid = threadIdx.x;
    int c = tid & 63;
    int m = blockIdx.x * 4 + (tid >> 6);
    const float* hrow = hidden + m * HID;
    const float* wrow = W2 + c * HID;

    float acc = b2[c];
    for (int p = 0; p < HID; p += 4) {
        float4 wv = *(const float4*)(wrow + p);
        float4 hv = *(const float4*)(hrow + p);
        acc += hv.x * wv.x + hv.y * wv.y + hv.z * wv.z + hv.w * wv.w;
    }
    out[m * 64 + c] = acc;

    float t0 = acc * W3[c];
    float t1 = acc * W3[64 + c];
#pragma unroll
    for (int off = 32; off > 0; off >>= 1) {
        t0 += __shfl_down(t0, off, 64);
        t1 += __shfl_down(t1, off, 64);
    }
    if (c == 0) {
        float2 pk;
        pk.x = t0 + b3[0];
        pk.y = t1 + b3[1];
        *(float2*)(out + 8192 + m * 2) = pk;
    }
}

// ---------------------------------------------------------------------------
extern "C" void kernel_launch(void* const* d_in, const int* in_sizes, int n_in,
                              void* d_out, int out_size, void* d_ws, size_t ws_size,
                              hipStream_t stream) {
    const float* x  = (const float*)d_in[0];
    const float* Wq = (const float*)d_in[1];
    const float* bq = (const float*)d_in[2];
    const float* Wk = (const float*)d_in[3];
    const float* bk = (const float*)d_in[4];
    const float* Wv = (const float*)d_in[5];
    const float* bv = (const float*)d_in[6];
    const float* Wo = (const float*)d_in[7];
    const float* bo = (const float*)d_in[8];
    const float* W1 = (const float*)d_in[9];
    const float* b1 = (const float*)d_in[10];
    const float* W2 = (const float*)d_in[11];
    const float* b2 = (const float*)d_in[12];
    const float* W3 = (const float*)d_in[13];
    const float* b3 = (const float*)d_in[14];
    float* out = (float*)d_out;

    // ws layout (bytes), total 12,812,288 (< 16 MiB, no overlays):
    //   [0,          8,192,000)  av fp32  [64000][32]
    //   [8,192,000, 12,288,000)  flat bf16 [128][16000]
    //   [12,288,000,12,812,288)  hidden fp32 [128][1024]
    float* av     = (float*)d_ws;
    u16*   flatbf = (u16*)((char*)d_ws + 8192000);
    float* hidden = (float*)((char*)d_ws + 12288000);

    attn_fused <<<dim3(1024), dim3(128), 0, stream>>>(x, Wq, bq, Wk, bk, Wv, bv, av);
    proj_kernel<<<dim3(8000), dim3(256), 0, stream>>>(av, Wo, bo, b1, flatbf, hidden);
    fc1_mfma   <<<dim3(320),  dim3(256), 0, stream>>>(flatbf, W1, hidden);
    fc2_kernel <<<dim3(32),   dim3(256), 0, stream>>>(hidden, W2, b2, W3, b3, out);
}

// Round 8
// 435.658 us; speedup vs baseline: 2.9145x; 1.0574x over previous
//
#include <hip/hip_runtime.h>

typedef unsigned short u16;
typedef __attribute__((ext_vector_type(8))) short short8;
typedef __attribute__((ext_vector_type(4))) float floatx4;

#define B_ 128
#define S_ 500
#define FCIN 16000
#define HID 1024
#define QSCL 0.72134752044448169f   // 0.5 * log2(e)

__device__ __forceinline__ float bf2f(u16 u) {
    union { unsigned u32; float f; } x;
    x.u32 = ((unsigned)u) << 16;
    return x.f;
}
__device__ __forceinline__ u16 f2bf(float f) {
    union { float f; unsigned u; } x;
    x.f = f;
    unsigned u = x.u;
    return (u16)((u + 0x7fff + ((u >> 16) & 1)) >> 16);
}

// ---------------------------------------------------------------------------
// K1: fused QKV + MFMA attention. Block = (b,h), 256 thr / 4 waves.
// Phase 1 (fp32 VALU): q,k,v from x. q,k stored in LDS as hi/lo split-bf16
// pairs [512][8] (rows 500-511 zero); v as bf16 V^T [4][520] (cols 500+ zero).
// Phase 2: scores via 2 chained MFMAs (exact fp32 product: [kh|kl]x[qh|ql] +
// [kl|kh]x[qh|ql]); exp2 fp32; P bf16 staged per-wave in LDS; PV as
// (AV)^T = mfma(A=V^T, B=P^T); rowsum in regs + 2 shfl_xor. av bf16 out.
// ---------------------------------------------------------------------------
__global__ __launch_bounds__(256) void attn_fused_mfma(
    const float* __restrict__ x,
    const float* __restrict__ Wq, const float* __restrict__ bq,
    const float* __restrict__ Wk, const float* __restrict__ bk,
    const float* __restrict__ Wv, const float* __restrict__ bv,
    u16* __restrict__ avbf)
{
    __shared__ float sWb[12 * 32];   // rows 0-3 Wq, 4-7 Wk, 8-11 Wv (head h)
    __shared__ float sBb[12];
    __shared__ u16 sQ8[512 * 8];     // [q][qh0..3, ql0..3]
    __shared__ u16 sK8[512 * 8];     // [key][kh0..3, kl0..3]
    __shared__ u16 sVT[4 * 520];     // [vcol][key]
    __shared__ u16 sP[4][640];       // per-wave P tile [q16][40]

    int tid = threadIdx.x;
    int bh = blockIdx.x, b = bh >> 3, h = bh & 7;

    for (int i = tid; i < 384; i += 256) {
        int r = i >> 5, d = i & 31;
        const float* src = (r < 4) ? (Wq + (h * 4 + r) * 32)
                         : (r < 8) ? (Wk + (h * 4 + r - 4) * 32)
                                   : (Wv + (h * 4 + r - 8) * 32);
        sWb[r * 32 + d] = src[d];
    }
    if (tid < 12)
        sBb[tid] = (tid < 4) ? bq[h * 4 + tid]
                 : (tid < 8) ? bk[h * 4 + tid - 4] : bv[h * 4 + tid - 8];
    if (tid < 32) sVT[(tid >> 3) * 520 + 512 + (tid & 7)] = 0;
    __syncthreads();

    for (int s = tid; s < 512; s += 256) {
        bool valid = (s < S_);
        const float* xr = x + ((size_t)b * S_ + (valid ? s : 0)) * 32;
        float4 xv[8];
#pragma unroll
        for (int cc = 0; cc < 8; ++cc) xv[cc] = *(const float4*)(xr + cc * 4);
#pragma unroll
        for (int r = 0; r < 12; ++r) {
            float acc = sBb[r];
            const float4* w4 = (const float4*)(sWb + r * 32);
#pragma unroll
            for (int cc = 0; cc < 8; ++cc) {
                float4 w = w4[cc];
                acc += xv[cc].x * w.x + xv[cc].y * w.y
                     + xv[cc].z * w.z + xv[cc].w * w.w;
            }
            if (!valid) acc = 0.f;
            if (r < 4) {
                float v = acc * QSCL;
                u16 hi = f2bf(v);
                sQ8[s * 8 + r]     = hi;
                sQ8[s * 8 + 4 + r] = f2bf(v - bf2f(hi));
            } else if (r < 8) {
                int j = r - 4;
                u16 hi = f2bf(acc);
                sK8[s * 8 + j]     = hi;
                sK8[s * 8 + 4 + j] = f2bf(acc - bf2f(hi));
            } else {
                sVT[(r - 8) * 520 + s] = f2bf(acc);
            }
        }
    }
    __syncthreads();

    int wid = tid >> 6, lane = tid & 63;
    int ln = lane & 15, kq = lane >> 4;
    u16* myP = sP[wid];
    const short8 z8 = {0, 0, 0, 0, 0, 0, 0, 0};
    floatx4 zero = {0.f, 0.f, 0.f, 0.f};

    for (int i = 0; i < 8; ++i) {
        int qt = wid + 4 * i;                        // q-tile [0,32)
        short8 qf = z8;
        if (kq == 0) qf = *(const short8*)(sQ8 + (qt * 16 + ln) * 8);

        floatx4 acc = zero;
        float rs = 0.f;

        for (int c = 0; c < 16; ++c) {
            short8 ka = z8, kb = z8;
            if (kq == 0) {
                ka = *(const short8*)(sK8 + ((2 * c) * 16 + ln) * 8);
                kb = *(const short8*)(sK8 + ((2 * c + 1) * 16 + ln) * 8);
            }
            short8 kas, kbs;
            kas[0] = ka[4]; kas[1] = ka[5]; kas[2] = ka[6]; kas[3] = ka[7];
            kas[4] = ka[0]; kas[5] = ka[1]; kas[6] = ka[2]; kas[7] = ka[3];
            kbs[0] = kb[4]; kbs[1] = kb[5]; kbs[2] = kb[6]; kbs[3] = kb[7];
            kbs[4] = kb[0]; kbs[5] = kb[1]; kbs[6] = kb[2]; kbs[7] = kb[3];

            floatx4 s1 = __builtin_amdgcn_mfma_f32_16x16x32_bf16(ka, qf, zero, 0, 0, 0);
            s1 = __builtin_amdgcn_mfma_f32_16x16x32_bf16(kas, qf, s1, 0, 0, 0);
            floatx4 s2 = __builtin_amdgcn_mfma_f32_16x16x32_bf16(kb, qf, zero, 0, 0, 0);
            s2 = __builtin_amdgcn_mfma_f32_16x16x32_bf16(kbs, qf, s2, 0, 0, 0);

            // C layout: col=ln=q, row=kq*4+r = local key
            float e10 = exp2f(s1[0]), e11 = exp2f(s1[1]),
                  e12 = exp2f(s1[2]), e13 = exp2f(s1[3]);
            float e20 = exp2f(s2[0]), e21 = exp2f(s2[1]),
                  e22 = exp2f(s2[2]), e23 = exp2f(s2[3]);

            rs += e10 + e11 + e12 + e13;
            float e2s = e20 + e21 + e22 + e23;
            rs += (c < 15 || kq == 0) ? e2s : 0.f;   // keys 500-511 excluded

            uint2 w1, w2;
            w1.x = (unsigned)f2bf(e10) | ((unsigned)f2bf(e11) << 16);
            w1.y = (unsigned)f2bf(e12) | ((unsigned)f2bf(e13) << 16);
            w2.x = (unsigned)f2bf(e20) | ((unsigned)f2bf(e21) << 16);
            w2.y = (unsigned)f2bf(e22) | ((unsigned)f2bf(e23) << 16);
            *(uint2*)(myP + ln * 40 + kq * 4)      = w1;   // local keys 0-15
            *(uint2*)(myP + ln * 40 + 16 + kq * 4) = w2;   // local keys 16-31

            short8 pf = *(const short8*)(myP + ln * 40 + kq * 8);
            short8 vf = z8;
            if (ln < 4)
                vf = *(const short8*)(sVT + ln * 520 + c * 32 + kq * 8);
            acc = __builtin_amdgcn_mfma_f32_16x16x32_bf16(vf, pf, acc, 0, 0, 0);
        }

        rs += __shfl_xor(rs, 16, 64);
        rs += __shfl_xor(rs, 32, 64);

        int q = qt * 16 + ln;
        if (kq == 0 && q < S_) {                     // D rows 0-3 = vcols
            float inv = 1.0f / rs;
            uint2 pk;
            pk.x = (unsigned)f2bf(acc[0] * inv) | ((unsigned)f2bf(acc[1] * inv) << 16);
            pk.y = (unsigned)f2bf(acc[2] * inv) | ((unsigned)f2bf(acc[3] * inv) << 16);
            *(uint2*)(avbf + ((size_t)(b * S_ + q) * 32 + h * 4)) = pk;
        }
    }
}

// ---------------------------------------------------------------------------
// K2: output projection via MFMA: flat = av @ Wo^T + bo (bf16 out).
// Also inits hidden[m][j] = b1[j] for fc1's atomic accumulation.
// ---------------------------------------------------------------------------
__global__ __launch_bounds__(256) void proj_mfma(
    const u16* __restrict__ avbf, const float* __restrict__ Wo,
    const float* __restrict__ bo, const float* __restrict__ b1,
    u16* __restrict__ flat, float* __restrict__ hidden)
{
    int tid = threadIdx.x;
    int gid = blockIdx.x * 256 + tid;
    if (gid < B_ * HID) hidden[gid] = b1[gid & (HID - 1)];

    int wid = tid >> 6, lane = tid & 63;
    int lm = lane & 15, kq = lane >> 4;
    int m0 = (blockIdx.x * 4 + wid) * 16;

    short8 af = *(const short8*)(avbf + (size_t)(m0 + lm) * 32 + kq * 8);
    floatx4 zero = {0.f, 0.f, 0.f, 0.f};
#pragma unroll
    for (int t2 = 0; t2 < 2; ++t2) {
        int d = t2 * 16 + lm;
        const float* wr = Wo + d * 32 + kq * 8;
        float4 w0 = *(const float4*)(wr);
        float4 w1 = *(const float4*)(wr + 4);
        short8 bf;
        bf[0] = (short)f2bf(w0.x); bf[1] = (short)f2bf(w0.y);
        bf[2] = (short)f2bf(w0.z); bf[3] = (short)f2bf(w0.w);
        bf[4] = (short)f2bf(w1.x); bf[5] = (short)f2bf(w1.y);
        bf[6] = (short)f2bf(w1.z); bf[7] = (short)f2bf(w1.w);
        floatx4 acc = __builtin_amdgcn_mfma_f32_16x16x32_bf16(af, bf, zero, 0, 0, 0);
        float bias = bo[d];
#pragma unroll
        for (int r = 0; r < 4; ++r) {
            int row = m0 + kq * 4 + r;
            flat[(size_t)row * 32 + d] = f2bf(acc[r] + bias);
        }
    }
}

// ---------------------------------------------------------------------------
// K3: FC1 via MFMA split-K (25 k-chunks x 16 n-groups = 400 blocks).
// ---------------------------------------------------------------------------
__global__ __launch_bounds__(256) void fc1_mfma(
    const u16* __restrict__ flatbf, const float* __restrict__ W1,
    float* __restrict__ hidden)
{
    int tid = threadIdx.x;
    int wid = tid >> 6, lane = tid & 63;
    int lm = lane & 15, kq = lane >> 4;
    int ng = blockIdx.x & 15, kc = blockIdx.x >> 4;   // kc in [0,25)
    int n0 = ng * 64 + wid * 16;

    floatx4 acc[8];
#pragma unroll
    for (int mt = 0; mt < 8; ++mt) acc[mt] = (floatx4){0.f, 0.f, 0.f, 0.f};

    const float* wrow = W1 + (size_t)(n0 + lm) * FCIN;
    const u16*  abase = flatbf + lm * FCIN;

    for (int step = 0; step < 20; ++step) {
        int kk = kc * 640 + step * 32 + kq * 8;
        float4 w0 = *(const float4*)(wrow + kk);
        float4 w1 = *(const float4*)(wrow + kk + 4);
        short8 bfr;
        bfr[0] = (short)f2bf(w0.x); bfr[1] = (short)f2bf(w0.y);
        bfr[2] = (short)f2bf(w0.z); bfr[3] = (short)f2bf(w0.w);
        bfr[4] = (short)f2bf(w1.x); bfr[5] = (short)f2bf(w1.y);
        bfr[6] = (short)f2bf(w1.z); bfr[7] = (short)f2bf(w1.w);
#pragma unroll
        for (int mt = 0; mt < 8; ++mt) {
            short8 afr = *(const short8*)(abase + mt * 16 * FCIN + kk);
            acc[mt] = __builtin_amdgcn_mfma_f32_16x16x32_bf16(afr, bfr, acc[mt], 0, 0, 0);
        }
    }

    int j = n0 + lm;
#pragma unroll
    for (int mt = 0; mt < 8; ++mt) {
#pragma unroll
        for (int r = 0; r < 4; ++r) {
            int m = mt * 16 + kq * 4 + r;
            atomicAdd(&hidden[m * HID + j], acc[mt][r]);
        }
    }
}

// ---------------------------------------------------------------------------
// K4: FC2 + FC3 (fp32 VALU). d_out fp32: [0,8192)=out1, [8192,8448)=out.
// ---------------------------------------------------------------------------
__global__ __launch_bounds__(256) void fc2_kernel(
    const float* __restrict__ hidden,
    const float* __restrict__ W2, const float* __restrict__ b2,
    const float* __restrict__ W3, const float* __restrict__ b3,
    float* __restrict__ out)
{
    int tid = threadIdx.x;
    int c = tid & 63;
    int m = blockIdx.x * 4 + (tid >> 6);
    const float* hrow = hidden + m * HID;
    const float* wrow = W2 + c * HID;

    float acc = b2[c];
    for (int p = 0; p < HID; p += 4) {
        float4 wv = *(const float4*)(wrow + p);
        float4 hv = *(const float4*)(hrow + p);
        acc += hv.x * wv.x + hv.y * wv.y + hv.z * wv.z + hv.w * wv.w;
    }
    out[m * 64 + c] = acc;

    float t0 = acc * W3[c];
    float t1 = acc * W3[64 + c];
#pragma unroll
    for (int off = 32; off > 0; off >>= 1) {
        t0 += __shfl_down(t0, off, 64);
        t1 += __shfl_down(t1, off, 64);
    }
    if (c == 0) {
        float2 pk;
        pk.x = t0 + b3[0];
        pk.y = t1 + b3[1];
        *(float2*)(out + 8192 + m * 2) = pk;
    }
}

// ---------------------------------------------------------------------------
extern "C" void kernel_launch(void* const* d_in, const int* in_sizes, int n_in,
                              void* d_out, int out_size, void* d_ws, size_t ws_size,
                              hipStream_t stream) {
    const float* x  = (const float*)d_in[0];
    const float* Wq = (const float*)d_in[1];
    const float* bq = (const float*)d_in[2];
    const float* Wk = (const float*)d_in[3];
    const float* bk = (const float*)d_in[4];
    const float* Wv = (const float*)d_in[5];
    const float* bv = (const float*)d_in[6];
    const float* Wo = (const float*)d_in[7];
    const float* bo = (const float*)d_in[8];
    const float* W1 = (const float*)d_in[9];
    const float* b1 = (const float*)d_in[10];
    const float* W2 = (const float*)d_in[11];
    const float* b2 = (const float*)d_in[12];
    const float* W3 = (const float*)d_in[13];
    const float* b3 = (const float*)d_in[14];
    float* out = (float*)d_out;

    // ws layout (bytes), total 8,716,288:
    //   [0,         4,096,000)  avbf bf16 [64000][32]
    //   [4,096,000, 8,192,000)  flat bf16 [128][16000]
    //   [8,192,000, 8,716,288)  hidden fp32 [128][1024]
    u16*   avbf   = (u16*)d_ws;
    u16*   flat   = (u16*)((char*)d_ws + 4096000);
    float* hidden = (float*)((char*)d_ws + 8192000);

    attn_fused_mfma<<<dim3(1024), dim3(256), 0, stream>>>(
        x, Wq, bq, Wk, bk, Wv, bv, avbf);
    proj_mfma <<<dim3(1000), dim3(256), 0, stream>>>(avbf, Wo, bo, b1, flat, hidden);
    fc1_mfma  <<<dim3(400),  dim3(256), 0, stream>>>(flat, W1, hidden);
    fc2_kernel<<<dim3(32),   dim3(256), 0, stream>>>(hidden, W2, b2, W3, b3, out);
}